// Round 4
// baseline (589.683 us; speedup 1.0000x reference)
//
#include <hip/hip_runtime.h>
#include <math.h>

#define BB    32
#define TT    1024
#define VV    1024
#define LM    128
#define SS    257        // 2*LM+1 extended states
#define SP    272        // floats per row = 1088 B = 17 full cache lines
#define RNORM 32         // renormalize every 32 DP steps (f64: huge margin)
#define PF    4          // DP prefetch ring depth

// ---------------------------------------------------------------------------
// Kernel A: ONE WAVE PER ROW (4 rows / 256-thr block), no barriers.
//  - wave loads its 1024-float row (4x float4/lane), stages in private LDS
//  - shuffle-butterfly max + sum(exp) -> LSE
//  - gathers 257 extended-label logits, centers by r = mean(gathered),
//    stores p = exp(x - r) in LINEAR fp32 + slot257 = LSE - r.
// ---------------------------------------------------------------------------
__global__ __launch_bounds__(256) void ctc_row_kernel(
    const float* __restrict__ ys_hat, const int* __restrict__ ys_pad,
    const int* __restrict__ hlens, float* __restrict__ lp)
{
    __shared__ float srow[4][VV];
    const int w    = threadIdx.x >> 6;
    const int lane = threadIdx.x & 63;
    const int row  = blockIdx.x * 4 + w;
    const int b    = row >> 10;            // T = 1024
    const int t    = row & (TT - 1);
    if (t >= hlens[b]) return;             // wave-uniform exit, no barrier dep

    const float* xr = ys_hat + (size_t)row * VV;
    float4 v[4];
    #pragma unroll
    for (int k = 0; k < 4; ++k) {
        v[k] = ((const float4*)xr)[lane + 64 * k];
        ((float4*)srow[w])[lane + 64 * k] = v[k];
    }
    float mx = -1e30f;
    #pragma unroll
    for (int k = 0; k < 4; ++k)
        mx = fmaxf(mx, fmaxf(fmaxf(v[k].x, v[k].y), fmaxf(v[k].z, v[k].w)));
    #pragma unroll
    for (int off = 32; off; off >>= 1) mx = fmaxf(mx, __shfl_xor(mx, off));
    float sm = 0.f;
    #pragma unroll
    for (int k = 0; k < 4; ++k)
        sm += __expf(v[k].x - mx) + __expf(v[k].y - mx) +
              __expf(v[k].z - mx) + __expf(v[k].w - mx);
    #pragma unroll
    for (int off = 32; off; off >>= 1) sm += __shfl_xor(sm, off);

    // gather: lane owns states s = 4*lane .. 4*lane+3 (contiguous -> float4 out)
    const int* lab = ys_pad + b * LM;
    const float xb = srow[w][0];                       // blank logit
    const float x1 = srow[w][lab[2 * lane]];           // state 4l+1
    const float x3 = srow[w][lab[2 * lane + 1]];       // state 4l+3

    float rsum = xb + x1 + xb + x3 + (lane == 0 ? xb : 0.f);  // +state 256
    #pragma unroll
    for (int off = 32; off; off >>= 1) rsum += __shfl_xor(rsum, off);
    const float r = rsum * (1.f / 257.f);

    float* lpo = lp + (size_t)row * SP;
    const float pb = __expf(xb - r);
    ((float4*)lpo)[lane] = make_float4(pb, __expf(x1 - r), pb, __expf(x3 - r));
    if (lane < 16) {                                   // slots 256..271: 1 full line
        float val = 0.f;
        if (lane == 0) val = pb;                       // state 256 (blank)
        if (lane == 1) val = mx + __logf(sm) - r;      // LSE - r
        lpo[256 + lane] = val;
    }
}

// ---------------------------------------------------------------------------
// Kernel B: ONE WAVE PER BATCH, alpha in FP64 registers (4 states/lane,
// lane63 also owns state 256), neighbor state via one __shfl_up(double),
// NO barriers in the hot loop, no transcendentals in the hot loop.
// new = (a + a_{s-1} + skip*a_{s-2}) * p.  FP64 range e^±708 makes both
// overflow (round-3 failure) and terminal underflow impossible with
// RNORM=32 (worst growth e^{7.4*32}=e^237).  Scale tracked exactly in clog.
// loss = sum_t(LSE_t - r_t) - clog - log(alpha[2L] + alpha[2L-1]).
// ---------------------------------------------------------------------------
__global__ __launch_bounds__(64) void ctc_dp_kernel(
    const float* __restrict__ lp_all, const int* __restrict__ ys_pad,
    const int* __restrict__ hlens, const int* __restrict__ ys_lens,
    float* __restrict__ out)
{
    __shared__ double sh[SS];
    const int b    = blockIdx.x;
    const int lane = threadIdx.x;
    const int hl   = hlens[b];
    const float* lp = lp_all + (size_t)b * TT * SP;

    // sum of (LSE_t - r_t) over t < hl
    float ss = 0.f;
    for (int t = lane; t < hl; t += 64) ss += lp[(size_t)t * SP + 257];
    #pragma unroll
    for (int off = 32; off; off >>= 1) ss += __shfl_xor(ss, off);

    // skip flags (labels contain no blanks; only the != test matters)
    const int* lab = ys_pad + b * LM;
    const bool skip1 = (lane > 0) && (lab[2 * lane] != lab[2 * lane - 1]);
    const bool skip3 = (lab[2 * lane + 1] != lab[2 * lane]);

    // t = 0 init: only states 0 and 1 live (both in lane 0)
    float4 q0 = ((const float4*)lp)[lane];
    double a0 = (lane == 0) ? (double)q0.x : 0.0;
    double a1 = (lane == 0) ? (double)q0.y : 0.0;
    double a2 = 0.0, a3 = 0.0, a4 = 0.0;
    double clog = 0.0;

    // prefetch ring: rows t = 1..PF   (hl >= 512 >> PF)
    float4 qr[PF]; float er[PF];
    #pragma unroll
    for (int j = 0; j < PF; ++j) {
        qr[j] = ((const float4*)(lp + (size_t)(1 + j) * SP))[lane];
        er[j] = lp[(size_t)(1 + j) * SP + 256];
    }

    for (int t = 1; t < hl; ++t) {
        const int j = (t - 1) & (PF - 1);
        const float4 q = qr[j];
        const float  e = er[j];
        int tp = t + PF; if (tp > hl - 1) tp = hl - 1;   // stay in written rows
        qr[j] = ((const float4*)(lp + (size_t)tp * SP))[lane];
        er[j] = lp[(size_t)tp * SP + 256];

        double n1 = __shfl_up(a3, 1);                    // state 4l-1 (lane l-1)
        if (lane == 0) n1 = 0.0;
        const double b0 = (a0 + n1) * (double)q.x;                      // even: no skip
        const double b1 = (a1 + a0 + (skip1 ? n1 : 0.0)) * (double)q.y; // s-2 = 4l-1 = n1
        const double b2 = (a2 + a1) * (double)q.z;
        const double b3 = (a3 + a2 + (skip3 ? a1 : 0.0)) * (double)q.w;
        const double b4 = (a4 + a3) * (double)e;                        // state 256
        a0 = b0; a1 = b1; a2 = b2; a3 = b3;
        a4 = (lane == 63) ? b4 : 0.0;

        if ((t & (RNORM - 1)) == 0) {
            double m = fmax(fmax(fmax(a0, a1), fmax(a2, a3)), a4);
            #pragma unroll
            for (int off = 32; off; off >>= 1) m = fmax(m, __shfl_xor(m, off));
            const double inv = 1.0 / m;                  // wave-uniform
            a0 *= inv; a1 *= inv; a2 *= inv; a3 *= inv; a4 *= inv;
            clog += log(m);                              // exact scale tracking
        }
    }

    sh[4 * lane]     = a0;
    sh[4 * lane + 1] = a1;
    sh[4 * lane + 2] = a2;
    sh[4 * lane + 3] = a3;
    if (lane == 63) sh[256] = a4;
    __syncthreads();                                     // single wave: cheap
    if (lane == 0) {
        const int L = ys_lens[b];
        const double aL = sh[2 * L] + sh[2 * L - 1];
        const double loss = (double)ss - (log(aL) + clog);
        atomicAdd(out, (float)(loss * (1.0 / (double)BB)));
    }
}

extern "C" void kernel_launch(void* const* d_in, const int* in_sizes, int n_in,
                              void* d_out, int out_size, void* d_ws, size_t ws_size,
                              hipStream_t stream) {
    const float* ys_hat  = (const float*)d_in[0];
    const int*   ys_pad  = (const int*)d_in[1];
    const int*   hlens   = (const int*)d_in[2];
    const int*   ys_lens = (const int*)d_in[3];
    float* out = (float*)d_out;

    float* lp_raw = (float*)d_ws;        // [B, T, SP] floats (~35.7 MB)

    hipMemsetAsync(d_out, 0, sizeof(float), stream);

    ctc_row_kernel<<<BB * TT / 4, 256, 0, stream>>>(ys_hat, ys_pad, hlens, lp_raw);
    ctc_dp_kernel<<<BB, 64, 0, stream>>>(lp_raw, ys_pad, hlens, ys_lens, out);
}

// Round 5
// 325.800 us; speedup vs baseline: 1.8100x; 1.8100x over previous
//
#include <hip/hip_runtime.h>
#include <math.h>

#define BB    32
#define TT    1024
#define VV    1024
#define LM    128
#define SS    257        // 2*LM+1 extended states
#define SP    272        // floats per row = 1088 B = 17 full cache lines
#define RNORM 32         // renormalize every 32 DP steps (f64: huge margin)
#define PF    8          // DP prefetch ring depth (STATIC indices -> registers)
#define RPW   8          // rows per wave in the row kernel

// ---------------------------------------------------------------------------
// Kernel A: one wave per 8 CONTIGUOUS rows, register double-buffered:
// next row's 4x float4 global loads are issued before processing the current
// row, so HBM latency overlaps the reduction work. Single fused online-
// softmax butterfly (max+sum together); center r = row max (drops the mean
// butterfly; any wave-uniform center is algebraically exact).
// Stores p = exp(x_ext - mx) fp32 + slot257 = LSE - mx = log(sum).
// ---------------------------------------------------------------------------
__global__ __launch_bounds__(256) void ctc_row_kernel(
    const float* __restrict__ ys_hat, const int* __restrict__ ys_pad,
    const int* __restrict__ hlens, float* __restrict__ lp)
{
    __shared__ float srow[4][VV];
    const int w    = threadIdx.x >> 6;
    const int lane = threadIdx.x & 63;
    const int gw   = blockIdx.x * 4 + w;      // 0..4095 global wave id
    const int b    = gw >> 7;                 // 128 waves per batch
    const int t0   = (gw & 127) * RPW;        // first frame of this wave
    const int hl   = hlens[b];
    int nrows = hl - t0;
    if (nrows <= 0) return;                   // wave-uniform exit
    if (nrows > RPW) nrows = RPW;

    const int lab0 = ys_pad[b * LM + 2 * lane];      // label for state 4l+1
    const int lab1 = ys_pad[b * LM + 2 * lane + 1];  // label for state 4l+3
    const float* xr  = ys_hat + ((size_t)b * TT + t0) * VV;
    float*       lpo = lp     + ((size_t)b * TT + t0) * SP;

    float4 va0, va1, va2, va3, vb0, vb1, vb2, vb3;
    {
        const float4* cx = (const float4*)xr;
        va0 = cx[lane]; va1 = cx[lane + 64]; va2 = cx[lane + 128]; va3 = cx[lane + 192];
    }

#define ROW_STEP(C0, C1, C2, C3, N0, N1, N2, N3)                               \
    {                                                                          \
        if (i + 1 < nrows) {  /* prefetch next row while we reduce this one */ \
            const float4* nx = (const float4*)(xr + (size_t)(i + 1) * VV);     \
            N0 = nx[lane]; N1 = nx[lane + 64];                                 \
            N2 = nx[lane + 128]; N3 = nx[lane + 192];                          \
        }                                                                      \
        float4* sw = (float4*)srow[w];                                         \
        sw[lane] = C0; sw[lane + 64] = C1;                                     \
        sw[lane + 128] = C2; sw[lane + 192] = C3;                              \
        float m = fmaxf(fmaxf(fmaxf(C0.x, C0.y), fmaxf(C0.z, C0.w)),          \
                        fmaxf(fmaxf(C1.x, C1.y), fmaxf(C1.z, C1.w)));          \
        m = fmaxf(m, fmaxf(fmaxf(fmaxf(C2.x, C2.y), fmaxf(C2.z, C2.w)),       \
                           fmaxf(fmaxf(C3.x, C3.y), fmaxf(C3.z, C3.w))));      \
        float s = __expf(C0.x - m) + __expf(C0.y - m) + __expf(C0.z - m) +     \
                  __expf(C0.w - m) + __expf(C1.x - m) + __expf(C1.y - m) +     \
                  __expf(C1.z - m) + __expf(C1.w - m) + __expf(C2.x - m) +     \
                  __expf(C2.y - m) + __expf(C2.z - m) + __expf(C2.w - m) +     \
                  __expf(C3.x - m) + __expf(C3.y - m) + __expf(C3.z - m) +     \
                  __expf(C3.w - m);                                            \
        _Pragma("unroll")                                                      \
        for (int off = 32; off; off >>= 1) {  /* fused max+sum butterfly */    \
            const float mo = __shfl_xor(m, off);                               \
            const float so = __shfl_xor(s, off);                               \
            const float mn = fmaxf(m, mo);                                     \
            s = s * __expf(m - mn) + so * __expf(mo - mn);                     \
            m = mn;                                                            \
        }                                                                      \
        const float xbv = srow[w][0];                                          \
        const float x1v = srow[w][lab0];                                       \
        const float x3v = srow[w][lab1];                                       \
        const float pb  = __expf(xbv - m);                                     \
        ((float4*)(lpo + (size_t)i * SP))[lane] =                              \
            make_float4(pb, __expf(x1v - m), pb, __expf(x3v - m));             \
        if (lane < 16) {  /* slots 256..271 = one full 64B line */             \
            float val = 0.f;                                                   \
            if (lane == 0) val = pb;            /* state 256 (blank) */        \
            if (lane == 1) val = __logf(s);     /* LSE - mx */                 \
            lpo[(size_t)i * SP + 256 + lane] = val;                            \
        }                                                                      \
    }

    int i = 0;
    for (;;) {
        ROW_STEP(va0, va1, va2, va3, vb0, vb1, vb2, vb3)
        if (++i >= nrows) break;
        ROW_STEP(vb0, vb1, vb2, vb3, va0, va1, va2, va3)
        if (++i >= nrows) break;
    }
#undef ROW_STEP
}

// ---------------------------------------------------------------------------
// Kernel B: ONE WAVE PER BATCH, alpha in FP64 registers (4 states/lane,
// lane63 also owns state 256), one __shfl_up(double) per step, no barriers,
// no transcendentals in the hot loop. Prefetch ring with STATIC indices
// (chunked + #pragma unroll) -- round 4's dynamic ring index sent the ring
// to scratch (VGPR_Count=32) and cost ~1000 cyc/step.
// All even states share the blank prob, so e(state 256) == q.x: no extra load.
// loss = sum_t(LSE_t - mx_t) - clog - log(alpha[2L] + alpha[2L-1]).
// ---------------------------------------------------------------------------
__global__ __launch_bounds__(64) void ctc_dp_kernel(
    const float* __restrict__ lp_all, const int* __restrict__ ys_pad,
    const int* __restrict__ hlens, const int* __restrict__ ys_lens,
    float* __restrict__ out)
{
    __shared__ double sh[SS];
    const int b    = blockIdx.x;
    const int lane = threadIdx.x;
    const int hl   = hlens[b];
    const float* lp = lp_all + (size_t)b * TT * SP;

    // sum of (LSE_t - mx_t) over t < hl
    float ss = 0.f;
    for (int t = lane; t < hl; t += 64) ss += lp[(size_t)t * SP + 257];
    #pragma unroll
    for (int off = 32; off; off >>= 1) ss += __shfl_xor(ss, off);

    // skip flags (labels contain no blanks; only the != test matters)
    const int* lab = ys_pad + b * LM;
    const bool skip1 = (lane > 0) && (lab[2 * lane] != lab[2 * lane - 1]);
    const bool skip3 = (lab[2 * lane + 1] != lab[2 * lane]);

    // t = 0 init: only states 0 and 1 live (both in lane 0)
    const float4 q0 = ((const float4*)lp)[lane];
    double a0 = (lane == 0) ? (double)q0.x : 0.0;
    double a1 = (lane == 0) ? (double)q0.y : 0.0;
    double a2 = 0.0, a3 = 0.0, a4 = 0.0;
    double clog = 0.0;

    // prime the ring: rows t = 1..PF (hl >= 512)
    float4 qr[PF];
    #pragma unroll
    for (int j = 0; j < PF; ++j)
        qr[j] = ((const float4*)(lp + (size_t)(1 + j) * SP))[lane];

    for (int t0 = 1; t0 < hl; t0 += PF) {
        #pragma unroll
        for (int j = 0; j < PF; ++j) {           // j static -> ring in VGPRs
            const int t = t0 + j;
            const float4 q = qr[j];
            int tp = t + PF; if (tp > hl - 1) tp = hl - 1;
            qr[j] = ((const float4*)(lp + (size_t)tp * SP))[lane];
            if (t < hl) {                        // wave-uniform
                double n1 = __shfl_up(a3, 1);    // state 4l-1 from lane l-1
                if (lane == 0) n1 = 0.0;
                const double c0 = (a0 + n1) * (double)q.x;
                const double c1 = (a1 + a0 + (skip1 ? n1 : 0.0)) * (double)q.y;
                const double c2 = (a2 + a1) * (double)q.z;
                const double c3 = (a3 + a2 + (skip3 ? a1 : 0.0)) * (double)q.w;
                const double c4 = (a4 + a3) * (double)q.x;   // state 256: blank
                a0 = c0; a1 = c1; a2 = c2; a3 = c3;
                a4 = (lane == 63) ? c4 : 0.0;

                if ((t & (RNORM - 1)) == 0) {
                    double m = fmax(fmax(fmax(a0, a1), fmax(a2, a3)), a4);
                    #pragma unroll
                    for (int off = 32; off; off >>= 1)
                        m = fmax(m, __shfl_xor(m, off));
                    const double inv = 1.0 / m;              // wave-uniform
                    a0 *= inv; a1 *= inv; a2 *= inv; a3 *= inv; a4 *= inv;
                    clog += log(m);                          // exact tracking
                }
            }
        }
    }

    sh[4 * lane]     = a0;
    sh[4 * lane + 1] = a1;
    sh[4 * lane + 2] = a2;
    sh[4 * lane + 3] = a3;
    if (lane == 63) sh[256] = a4;
    __syncthreads();                                         // single wave
    if (lane == 0) {
        const int L = ys_lens[b];
        const double aL = sh[2 * L] + sh[2 * L - 1];
        const double loss = (double)ss - (log(aL) + clog);
        atomicAdd(out, (float)(loss * (1.0 / (double)BB)));
    }
}

extern "C" void kernel_launch(void* const* d_in, const int* in_sizes, int n_in,
                              void* d_out, int out_size, void* d_ws, size_t ws_size,
                              hipStream_t stream) {
    const float* ys_hat  = (const float*)d_in[0];
    const int*   ys_pad  = (const int*)d_in[1];
    const int*   hlens   = (const int*)d_in[2];
    const int*   ys_lens = (const int*)d_in[3];
    float* out = (float*)d_out;

    float* lp_raw = (float*)d_ws;        // [B, T, SP] floats (~35.7 MB)

    hipMemsetAsync(d_out, 0, sizeof(float), stream);

    ctc_row_kernel<<<BB * TT / (4 * RPW), 256, 0, stream>>>(ys_hat, ys_pad, hlens, lp_raw);
    ctc_dp_kernel<<<BB, 64, 0, stream>>>(lp_raw, ys_pad, hlens, ys_lens, out);
}